// Round 1
// baseline (913.959 us; speedup 1.0000x reference)
//
#include <hip/hip_runtime.h>
#include <hip/hip_bf16.h>

#define H 128
#define LN_EPS 1e-5f

// ---------------- utility kernels ----------------

__global__ void zero_int_kernel(int* __restrict__ p, int n) {
  int i = blockIdx.x * blockDim.x + threadIdx.x;
  if (i < n) p[i] = 0;
}

// cvec[j] = bf[j] + sum_{r<128} Wf[r][j]   (the ones @ Wf[:128] term)
__global__ void prep_cvec_kernel(const float* __restrict__ Wf, const float* __restrict__ bf,
                                 float* __restrict__ cvec) {
  int j = threadIdx.x;
  float s = bf[j];
  for (int r = 0; r < H; ++r) s += Wf[r * H + j];
  cvec[j] = s;
}

__global__ void count_kernel(const int* __restrict__ ei, int E, int* __restrict__ cnt) {
  int e = blockIdx.x * blockDim.x + threadIdx.x;
  if (e < E) atomicAdd(&cnt[ei[E + e]], 1);  // dst = ei[1][e]
}

__global__ __launch_bounds__(1024) void scan_kernel(const int* __restrict__ cnt,
                                                    int* __restrict__ off,
                                                    int* __restrict__ pos, int N) {
  __shared__ int wtot[16];
  __shared__ int wbase[16];
  __shared__ int s_btot;
  __shared__ int s_carry;
  int tid = threadIdx.x, lane = tid & 63, wid = tid >> 6;
  if (tid == 0) s_carry = 0;
  __syncthreads();
  for (int base = 0; base < N; base += 4096) {
    int i0 = base + tid * 4;
    int v[4];
#pragma unroll
    for (int j = 0; j < 4; ++j) v[j] = (i0 + j < N) ? cnt[i0 + j] : 0;
    int s = v[0] + v[1] + v[2] + v[3];
    int incl = s;
#pragma unroll
    for (int o = 1; o < 64; o <<= 1) {
      int t = __shfl_up(incl, o, 64);
      if (lane >= o) incl += t;
    }
    if (lane == 63) wtot[wid] = incl;
    __syncthreads();
    if (tid == 0) {
      int run = 0;
      for (int w = 0; w < 16; ++w) { wbase[w] = run; run += wtot[w]; }
      s_btot = run;
    }
    __syncthreads();
    int e0 = s_carry + wbase[wid] + (incl - s);
#pragma unroll
    for (int j = 0; j < 4; ++j) {
      if (i0 + j < N) { off[i0 + j] = e0; pos[i0 + j] = e0; }
      e0 += v[j];
    }
    __syncthreads();
    if (tid == 0) s_carry += s_btot;
    __syncthreads();
  }
  if (tid == 0) off[N] = s_carry;
}

__global__ void fill_kernel(const int* __restrict__ ei, const float* __restrict__ ew, int E,
                            int* __restrict__ pos, int* __restrict__ csr_src,
                            float* __restrict__ csr_w) {
  int e = blockIdx.x * blockDim.x + threadIdx.x;
  if (e < E) {
    int d = ei[E + e];
    int p = atomicAdd(&pos[d], 1);
    csr_src[p] = ei[e];
    csr_w[p] = ew[e];
  }
}

// ---------------- edge weight MLP: ew = sigmoid(relu(af@We1+be1)@We2+be2) ----------------
__global__ __launch_bounds__(256) void edge_weight_kernel(
    const float* __restrict__ af, const float* __restrict__ We1, const float* __restrict__ be1,
    const float* __restrict__ We2, const float* __restrict__ be2, float* __restrict__ ew, int E) {
  __shared__ float sW1[8][H];
  __shared__ float sb1[H];
  __shared__ float sW2[H];
  for (int i = threadIdx.x; i < 8 * H; i += blockDim.x) sW1[i >> 7][i & 127] = We1[i];
  for (int i = threadIdx.x; i < H; i += blockDim.x) { sb1[i] = be1[i]; sW2[i] = We2[i]; }
  __syncthreads();
  float b2 = be2[0];
  for (int e = blockIdx.x * blockDim.x + threadIdx.x; e < E; e += gridDim.x * blockDim.x) {
    const float* ap = &af[(size_t)e * 8];
    float4 v0 = *(const float4*)&ap[0];
    float4 v1 = *(const float4*)&ap[4];
    float a0 = v0.x, a1 = v0.y, a2 = v0.z, a3 = v0.w;
    float a4 = v1.x, a5 = v1.y, a6 = v1.z, a7 = v1.w;
    float acc = 0.f;
#pragma unroll 4
    for (int j = 0; j < H; ++j) {
      float t = sb1[j];
      t += a0 * sW1[0][j]; t += a1 * sW1[1][j]; t += a2 * sW1[2][j]; t += a3 * sW1[3][j];
      t += a4 * sW1[4][j]; t += a5 * sW1[5][j]; t += a6 * sW1[6][j]; t += a7 * sW1[7][j];
      t = fmaxf(t, 0.f);
      acc += t * sW2[j];
    }
    float s = acc + b2;
    ew[e] = 1.f / (1.f + expf(-s));
  }
}

// ---------------- generic GEMM: Y = act(X1@W1 [+ X2@W2] + bias), shapes [M,128]x[128,128] ----------------
template <bool DUAL, bool RELU>
__global__ __launch_bounds__(256) void gemm128_kernel(
    const float* __restrict__ X1, const float* __restrict__ W1,
    const float* __restrict__ X2, const float* __restrict__ W2,
    const float* __restrict__ bias, float* __restrict__ Y, int M) {
  __shared__ float As[32][132];  // [k][m], padded
  __shared__ float Bs[32][132];  // [k][n], padded
  int block_m = blockIdx.x * 128;
  int tid = threadIdx.x;
  int tc = tid & 15, tr = tid >> 4;  // 16x16 thread grid, 8x8 per thread
  float acc[8][8] = {};
  const int nchunk = DUAL ? 8 : 4;
  for (int kk = 0; kk < nchunk; ++kk) {
    const float* X = (DUAL && kk >= 4) ? X2 : X1;
    const float* W = (DUAL && kk >= 4) ? W2 : W1;
    int k0 = (DUAL && kk >= 4) ? (kk - 4) * 32 : kk * 32;
    __syncthreads();
#pragma unroll
    for (int i = 0; i < 4; ++i) {  // stage A transposed: 128 rows x 32 k
      int s = tid + i * 256;
      int row = s >> 3, c4 = (s & 7) * 4;
      int gm = block_m + row;
      float4 v = (gm < M) ? *(const float4*)&X[(size_t)gm * H + k0 + c4]
                          : make_float4(0.f, 0.f, 0.f, 0.f);
      As[c4 + 0][row] = v.x; As[c4 + 1][row] = v.y; As[c4 + 2][row] = v.z; As[c4 + 3][row] = v.w;
    }
#pragma unroll
    for (int i = 0; i < 4; ++i) {  // stage B: 32 k x 128 n
      int s = tid + i * 256;
      int row = s >> 5, c4 = (s & 31) * 4;
      float4 v = *(const float4*)&W[(size_t)(k0 + row) * H + c4];
      *(float4*)&Bs[row][c4] = v;
    }
    __syncthreads();
#pragma unroll 4
    for (int k = 0; k < 32; ++k) {
      float a[8], b[8];
      *(float4*)&a[0] = *(const float4*)&As[k][tr * 8];
      *(float4*)&a[4] = *(const float4*)&As[k][tr * 8 + 4];
      *(float4*)&b[0] = *(const float4*)&Bs[k][tc * 8];
      *(float4*)&b[4] = *(const float4*)&Bs[k][tc * 8 + 4];
#pragma unroll
      for (int i = 0; i < 8; ++i)
#pragma unroll
        for (int j = 0; j < 8; ++j) acc[i][j] += a[i] * b[j];
    }
  }
  float bb[8] = {0.f, 0.f, 0.f, 0.f, 0.f, 0.f, 0.f, 0.f};
  if (bias) {
    *(float4*)&bb[0] = *(const float4*)&bias[tc * 8];
    *(float4*)&bb[4] = *(const float4*)&bias[tc * 8 + 4];
  }
#pragma unroll
  for (int i = 0; i < 8; ++i) {
    int gm = block_m + tr * 8 + i;
    if (gm >= M) break;
    float tmp[8];
#pragma unroll
    for (int j = 0; j < 8; ++j) {
      float v = acc[i][j] + bb[j];
      if (RELU) v = fmaxf(v, 0.f);
      tmp[j] = v;
    }
    *(float4*)&Y[(size_t)gm * H + tc * 8] = *(float4*)&tmp[0];
    *(float4*)&Y[(size_t)gm * H + tc * 8 + 4] = *(float4*)&tmp[4];
  }
}

// ---------------- gather: agg[n] = sum_in-edges w * x[src]  (wave per node) ----------------
__global__ __launch_bounds__(256) void gather_agg_kernel(
    const float* __restrict__ x, const int* __restrict__ off, const int* __restrict__ csr_src,
    const float* __restrict__ csr_w, float* __restrict__ agg, int N) {
  int gw = (blockIdx.x * blockDim.x + threadIdx.x) >> 6;
  int lane = threadIdx.x & 63;
  int nw = (gridDim.x * blockDim.x) >> 6;
  for (int n = gw; n < N; n += nw) {
    int s0 = off[n], s1 = off[n + 1];
    float ax = 0.f, ay = 0.f;
    for (int idx = s0; idx < s1; ++idx) {
      int src = csr_src[idx];
      float w = csr_w[idx];
      float2 v = *(const float2*)&x[(size_t)src * H + lane * 2];
      ax += w * v.x;
      ay += w * v.y;
    }
    float2 r = make_float2(ax, ay);
    *(float2*)&agg[(size_t)n * H + lane * 2] = r;
  }
}

// ---------------- LayerNorm + relu + residual: x = relu(LN(h)*g+b) + x  (wave per row) ----------------
__global__ __launch_bounds__(256) void ln_relu_res_kernel(
    const float* __restrict__ h, float* __restrict__ x, const float* __restrict__ gamma,
    const float* __restrict__ beta, int N) {
  int gw = (blockIdx.x * blockDim.x + threadIdx.x) >> 6;
  int lane = threadIdx.x & 63;
  int nw = (gridDim.x * blockDim.x) >> 6;
  for (int n = gw; n < N; n += nw) {
    float2 v = *(const float2*)&h[(size_t)n * H + lane * 2];
    float tot = v.x + v.y;
#pragma unroll
    for (int o = 32; o > 0; o >>= 1) tot += __shfl_xor(tot, o, 64);
    float mu = tot * (1.0f / H);
    float d0 = v.x - mu, d1 = v.y - mu;
    float s2 = d0 * d0 + d1 * d1;
#pragma unroll
    for (int o = 32; o > 0; o >>= 1) s2 += __shfl_xor(s2, o, 64);
    float r = rsqrtf(s2 * (1.0f / H) + LN_EPS);
    float2 g = *(const float2*)&gamma[lane * 2];
    float2 b = *(const float2*)&beta[lane * 2];
    float2 xo = *(const float2*)&x[(size_t)n * H + lane * 2];
    float o0 = fmaxf(d0 * r * g.x + b.x, 0.f) + xo.x;
    float o1 = fmaxf(d1 * r * g.y + b.y, 0.f) + xo.y;
    float2 res = make_float2(o0, o1);
    *(float2*)&x[(size_t)n * H + lane * 2] = res;
  }
}

// ---------------- edge decoder: out[e] = relu(A[src]+B[dst]+af@Wd1c)·Wd2 + bd2 (wave per edge) ----------------
__global__ __launch_bounds__(256) void edge_out_kernel(
    const int* __restrict__ ei, const float* __restrict__ af, const float* __restrict__ A,
    const float* __restrict__ B, const float* __restrict__ Wd1c, const float* __restrict__ Wd2,
    const float* __restrict__ bd2, float* __restrict__ out, int E) {
  __shared__ float sWc[8][H];
  __shared__ float sW2[H];
  for (int i = threadIdx.x; i < 8 * H; i += blockDim.x) sWc[i >> 7][i & 127] = Wd1c[i];
  for (int i = threadIdx.x; i < H; i += blockDim.x) sW2[i] = Wd2[i];
  __syncthreads();
  int gw = (blockIdx.x * blockDim.x + threadIdx.x) >> 6;
  int lane = threadIdx.x & 63;
  int nw = (gridDim.x * blockDim.x) >> 6;
  float b2 = bd2[0];
  for (int e = gw; e < E; e += nw) {
    int s = ei[e], d = ei[E + e];
    float2 va = *(const float2*)&A[(size_t)s * H + lane * 2];
    float2 vb = *(const float2*)&B[(size_t)d * H + lane * 2];
    float t0 = va.x + vb.x, t1 = va.y + vb.y;
#pragma unroll
    for (int i = 0; i < 8; ++i) {
      float a = af[(size_t)e * 8 + i];
      t0 += a * sWc[i][lane * 2];
      t1 += a * sWc[i][lane * 2 + 1];
    }
    t0 = fmaxf(t0, 0.f);
    t1 = fmaxf(t1, 0.f);
    float p = t0 * sW2[lane * 2] + t1 * sW2[lane * 2 + 1];
#pragma unroll
    for (int o = 32; o > 0; o >>= 1) p += __shfl_xor(p, o, 64);
    if (lane == 0) out[e] = p + b2;
  }
}

// ---------------- launch ----------------
extern "C" void kernel_launch(void* const* d_in, const int* in_sizes, int n_in, void* d_out,
                              int out_size, void* d_ws, size_t ws_size, hipStream_t stream) {
  const int* ei = (const int*)d_in[0];
  const float* af = (const float*)d_in[1];
  const float* h_old = (const float*)d_in[2];
  const float* Wf = (const float*)d_in[4];
  const float* bf = (const float*)d_in[5];
  const float* We1 = (const float*)d_in[6];
  const float* be1 = (const float*)d_in[7];
  const float* We2 = (const float*)d_in[8];
  const float* be2 = (const float*)d_in[9];
  const float* Wrel = (const float*)d_in[10];
  const float* brel = (const float*)d_in[11];
  const float* Wroot = (const float*)d_in[12];
  const float* gamma = (const float*)d_in[13];
  const float* beta = (const float*)d_in[14];
  const float* Wd1 = (const float*)d_in[15];
  const float* bd1 = (const float*)d_in[16];
  const float* Wd2 = (const float*)d_in[17];
  const float* bd2 = (const float*)d_in[18];
  const int N = in_sizes[2] / H;
  const int E = in_sizes[1] / 8;
  float* out = (float*)d_out;

  char* p = (char*)d_ws;
  auto alloc = [&](size_t b) { char* r = p; p += (b + 255) & ~(size_t)255; return r; };
  int* cnt = (int*)alloc((size_t)N * 4);
  int* pos = (int*)alloc((size_t)N * 4);
  int* off = (int*)alloc((size_t)(N + 1) * 4);
  int* csr_src = (int*)alloc((size_t)E * 4);
  float* csr_w = (float*)alloc((size_t)E * 4);
  float* ew = (float*)alloc((size_t)E * 4);
  float* cvec = (float*)alloc(H * 4);
  float* x = (float*)alloc((size_t)N * H * 4);
  float* h = (float*)alloc((size_t)N * H * 4);
  float* agg = (float*)alloc((size_t)N * H * 4);
  float* A = agg;   // reuse after layer loop
  float* Bb = h;    // reuse after layer loop

  hipLaunchKernelGGL(zero_int_kernel, dim3((N + 255) / 256), dim3(256), 0, stream, cnt, N);
  hipLaunchKernelGGL(prep_cvec_kernel, dim3(1), dim3(H), 0, stream, Wf, bf, cvec);
  hipLaunchKernelGGL(count_kernel, dim3((E + 255) / 256), dim3(256), 0, stream, ei, E, cnt);
  hipLaunchKernelGGL(scan_kernel, dim3(1), dim3(1024), 0, stream, cnt, off, pos, N);
  hipLaunchKernelGGL(edge_weight_kernel, dim3(2048), dim3(256), 0, stream, af, We1, be1, We2,
                     be2, ew, E);
  hipLaunchKernelGGL(fill_kernel, dim3((E + 255) / 256), dim3(256), 0, stream, ei, ew, E, pos,
                     csr_src, csr_w);

  int gblocks = (N + 127) / 128;
  // x = relu(h_old @ Wf[128:256] + cvec)
  hipLaunchKernelGGL((gemm128_kernel<false, true>), dim3(gblocks), dim3(256), 0, stream, h_old,
                     Wf + H * H, (const float*)nullptr, (const float*)nullptr, cvec, x, N);

  for (int l = 0; l < 3; ++l) {
    hipLaunchKernelGGL(gather_agg_kernel, dim3((N + 3) / 4), dim3(256), 0, stream, x, off,
                       csr_src, csr_w, agg, N);
    hipLaunchKernelGGL((gemm128_kernel<true, false>), dim3(gblocks), dim3(256), 0, stream, agg,
                       Wrel + (size_t)l * H * H, x, Wroot + (size_t)l * H * H, brel + l * H, h, N);
    hipLaunchKernelGGL(ln_relu_res_kernel, dim3((N + 3) / 4), dim3(256), 0, stream, h, x,
                       gamma + l * H, beta + l * H, N);
  }

  // decoder per-node projections: A = x@Wd1[0:128] + bd1 ; B = x@Wd1[128:256]
  hipLaunchKernelGGL((gemm128_kernel<false, false>), dim3(gblocks), dim3(256), 0, stream, x, Wd1,
                     (const float*)nullptr, (const float*)nullptr, bd1, A, N);
  hipLaunchKernelGGL((gemm128_kernel<false, false>), dim3(gblocks), dim3(256), 0, stream, x,
                     Wd1 + H * H, (const float*)nullptr, (const float*)nullptr,
                     (const float*)nullptr, Bb, N);
  hipLaunchKernelGGL(edge_out_kernel, dim3(4096), dim3(256), 0, stream, ei, af, A, Bb,
                     Wd1 + 2 * H * H, Wd2, bd2, out, E);
}

// Round 2
// 688.421 us; speedup vs baseline: 1.3276x; 1.3276x over previous
//
#include <hip/hip_runtime.h>
#include <hip/hip_bf16.h>

#define H 128
#define LN_EPS 1e-5f

typedef __attribute__((ext_vector_type(8))) short bf16x8;
typedef __attribute__((ext_vector_type(4))) float f32x4;

static __device__ __forceinline__ unsigned short f2bf(float f) {
  unsigned u = __float_as_uint(f);
  unsigned r = (u + 0x7fff + ((u >> 16) & 1)) >> 16;
  return (unsigned short)r;
}
static __device__ __forceinline__ float bf2f(unsigned short s) {
  return __uint_as_float(((unsigned)s) << 16);
}

// ---------------- utility kernels ----------------

__global__ void zero_int_kernel(int* __restrict__ p, int n) {
  int i = blockIdx.x * blockDim.x + threadIdx.x;
  if (i < n) p[i] = 0;
}

// cvec[j] = bf[j] + sum_{r<128} Wf[r][j]   (the ones @ Wf[:128] term)
__global__ void prep_cvec_kernel(const float* __restrict__ Wf, const float* __restrict__ bf,
                                 float* __restrict__ cvec) {
  int j = threadIdx.x;
  float s = bf[j];
  for (int r = 0; r < H; ++r) s += Wf[r * H + j];
  cvec[j] = s;
}

__global__ void count_kernel(const int* __restrict__ ei, int E, int* __restrict__ cnt) {
  int e = blockIdx.x * blockDim.x + threadIdx.x;
  if (e < E) atomicAdd(&cnt[ei[E + e]], 1);  // dst = ei[1][e]
}

__global__ __launch_bounds__(1024) void scan_kernel(const int* __restrict__ cnt,
                                                    int* __restrict__ off,
                                                    int* __restrict__ pos, int N) {
  __shared__ int wtot[16];
  __shared__ int wbase[16];
  __shared__ int s_btot;
  __shared__ int s_carry;
  int tid = threadIdx.x, lane = tid & 63, wid = tid >> 6;
  if (tid == 0) s_carry = 0;
  __syncthreads();
  for (int base = 0; base < N; base += 4096) {
    int i0 = base + tid * 4;
    int v[4];
#pragma unroll
    for (int j = 0; j < 4; ++j) v[j] = (i0 + j < N) ? cnt[i0 + j] : 0;
    int s = v[0] + v[1] + v[2] + v[3];
    int incl = s;
#pragma unroll
    for (int o = 1; o < 64; o <<= 1) {
      int t = __shfl_up(incl, o, 64);
      if (lane >= o) incl += t;
    }
    if (lane == 63) wtot[wid] = incl;
    __syncthreads();
    if (tid == 0) {
      int run = 0;
      for (int w = 0; w < 16; ++w) { wbase[w] = run; run += wtot[w]; }
      s_btot = run;
    }
    __syncthreads();
    int e0 = s_carry + wbase[wid] + (incl - s);
#pragma unroll
    for (int j = 0; j < 4; ++j) {
      if (i0 + j < N) { off[i0 + j] = e0; pos[i0 + j] = e0; }
      e0 += v[j];
    }
    __syncthreads();
    if (tid == 0) s_carry += s_btot;
    __syncthreads();
  }
  if (tid == 0) off[N] = s_carry;
}

__global__ void fill_kernel(const int* __restrict__ ei, const float* __restrict__ ew, int E,
                            int* __restrict__ pos, int* __restrict__ csr_src,
                            float* __restrict__ csr_w) {
  int e = blockIdx.x * blockDim.x + threadIdx.x;
  if (e < E) {
    int d = ei[E + e];
    int p = atomicAdd(&pos[d], 1);
    csr_src[p] = ei[e];
    csr_w[p] = ew[e];
  }
}

// f32 -> bf16 bulk convert (n multiple of 8)
__global__ __launch_bounds__(256) void cvt_bf16_kernel(const float* __restrict__ in,
                                                       unsigned short* __restrict__ out,
                                                       long n) {
  long i = ((long)blockIdx.x * blockDim.x + threadIdx.x) * 8;
  if (i >= n) return;
  float4 v0 = *(const float4*)&in[i];
  float4 v1 = *(const float4*)&in[i + 4];
  unsigned short t[8];
  t[0] = f2bf(v0.x); t[1] = f2bf(v0.y); t[2] = f2bf(v0.z); t[3] = f2bf(v0.w);
  t[4] = f2bf(v1.x); t[5] = f2bf(v1.y); t[6] = f2bf(v1.z); t[7] = f2bf(v1.w);
  *(uint4*)&out[i] = *(uint4*)t;
}

// pack 9 [128x128] weight matrices into MFMA B-fragment layout:
// wpk[m*16384 + ((kk*8+nf)*64 + l)*8 + j] = bf16(W[kk*32 + (l>>4)*8 + j][nf*16 + (l&15)])
__global__ __launch_bounds__(256) void pack_w_kernel(const float* __restrict__ Wf,
                                                     const float* __restrict__ Wrel,
                                                     const float* __restrict__ Wroot,
                                                     const float* __restrict__ Wd1,
                                                     unsigned short* __restrict__ wpk) {
  int id = blockIdx.x * blockDim.x + threadIdx.x;  // 0 .. 9*2048-1
  if (id >= 9 * 2048) return;
  int l = id & 63, nf = (id >> 6) & 7, kk = (id >> 9) & 3, m = id >> 11;
  const float* src;
  if (m == 0) src = Wf + H * H;                       // Wf2 (h_old part)
  else if (m <= 3) src = Wrel + (size_t)(m - 1) * H * H;
  else if (m <= 6) src = Wroot + (size_t)(m - 4) * H * H;
  else src = Wd1 + (size_t)(m - 7) * H * H;           // Wd1a, Wd1b
  int col = nf * 16 + (l & 15);
  int kbase = kk * 32 + (l >> 4) * 8;
  unsigned short t[8];
#pragma unroll
  for (int j = 0; j < 8; ++j) t[j] = f2bf(src[(size_t)(kbase + j) * H + col]);
  *(uint4*)&wpk[(size_t)id * 8] = *(uint4*)t;
}

// ---------------- edge weight MLP: ew = sigmoid(relu(af@We1+be1)@We2+be2) ----------------
__global__ __launch_bounds__(256) void edge_weight_kernel(
    const float* __restrict__ af, const float* __restrict__ We1, const float* __restrict__ be1,
    const float* __restrict__ We2, const float* __restrict__ be2, float* __restrict__ ew, int E) {
  __shared__ float sW1[8][H];
  __shared__ float sb1[H];
  __shared__ float sW2[H];
  for (int i = threadIdx.x; i < 8 * H; i += blockDim.x) sW1[i >> 7][i & 127] = We1[i];
  for (int i = threadIdx.x; i < H; i += blockDim.x) { sb1[i] = be1[i]; sW2[i] = We2[i]; }
  __syncthreads();
  float b2 = be2[0];
  for (int e = blockIdx.x * blockDim.x + threadIdx.x; e < E; e += gridDim.x * blockDim.x) {
    const float* ap = &af[(size_t)e * 8];
    float4 v0 = *(const float4*)&ap[0];
    float4 v1 = *(const float4*)&ap[4];
    float a0 = v0.x, a1 = v0.y, a2 = v0.z, a3 = v0.w;
    float a4 = v1.x, a5 = v1.y, a6 = v1.z, a7 = v1.w;
    float acc = 0.f;
#pragma unroll 4
    for (int j = 0; j < H; ++j) {
      float t = sb1[j];
      t += a0 * sW1[0][j]; t += a1 * sW1[1][j]; t += a2 * sW1[2][j]; t += a3 * sW1[3][j];
      t += a4 * sW1[4][j]; t += a5 * sW1[5][j]; t += a6 * sW1[6][j]; t += a7 * sW1[7][j];
      t = fmaxf(t, 0.f);
      acc += t * sW2[j];
    }
    float s = acc + b2;
    ew[e] = 1.f / (1.f + expf(-s));
  }
}

// ---------------- MFMA GEMM: Y = act(X1@W1 [+ X2@W2] + bias) ----------------
// X row-major bf16 [M,128]; W pre-packed fragment layout; OUT_MODE 0: f32, 1: bf16+relu, 2: bf16
template <bool DUAL, int OUT_MODE>
__global__ __launch_bounds__(256) void mfma_gemm_kernel(
    const unsigned short* __restrict__ X1, const unsigned short* __restrict__ Wp1,
    const unsigned short* __restrict__ X2, const unsigned short* __restrict__ Wp2,
    const float* __restrict__ bias, void* __restrict__ Yv, int M) {
  int l = threadIdx.x & 63, w = threadIdx.x >> 6;
  int lr = l & 15, lg = l >> 4;
  int m0 = blockIdx.x * 256 + w * 64;
  f32x4 acc[4][8] = {};
  const int nkk = DUAL ? 8 : 4;
  for (int kk = 0; kk < nkk; ++kk) {
    const unsigned short* X = (DUAL && kk >= 4) ? X2 : X1;
    const unsigned short* Wp = (DUAL && kk >= 4) ? Wp2 : Wp1;
    int k4 = kk & 3;
    bf16x8 a[4];
#pragma unroll
    for (int mi = 0; mi < 4; ++mi) {
      int row = m0 + mi * 16 + lr;
      if (row >= M) row = M - 1;
      a[mi] = *(const bf16x8*)&X[(size_t)row * H + k4 * 32 + lg * 8];
    }
#pragma unroll
    for (int nf = 0; nf < 8; ++nf) {
      bf16x8 b = *(const bf16x8*)&Wp[(size_t)(k4 * 8 + nf) * 512 + l * 8];
#pragma unroll
      for (int mi = 0; mi < 4; ++mi)
        acc[mi][nf] = __builtin_amdgcn_mfma_f32_16x16x32_bf16(a[mi], b, acc[mi][nf], 0, 0, 0);
    }
  }
  float bv[8];
#pragma unroll
  for (int nf = 0; nf < 8; ++nf) bv[nf] = bias ? bias[nf * 16 + lr] : 0.f;
#pragma unroll
  for (int mi = 0; mi < 4; ++mi) {
#pragma unroll
    for (int r = 0; r < 4; ++r) {
      int row = m0 + mi * 16 + lg * 4 + r;
      if (row < M) {
#pragma unroll
        for (int nf = 0; nf < 8; ++nf) {
          float v = acc[mi][nf][r] + bv[nf];
          if (OUT_MODE == 1) v = fmaxf(v, 0.f);
          int col = nf * 16 + lr;
          if (OUT_MODE == 0) ((float*)Yv)[(size_t)row * H + col] = v;
          else ((unsigned short*)Yv)[(size_t)row * H + col] = f2bf(v);
        }
      }
    }
  }
}

// ---------------- gather: agg[n] = sum_in-edges w * x[src]  (wave per node, bf16) ----------------
__global__ __launch_bounds__(256) void gather_agg_bf_kernel(
    const unsigned short* __restrict__ xbf, const int* __restrict__ off,
    const int* __restrict__ csr_src, const float* __restrict__ csr_w,
    unsigned short* __restrict__ aggbf, int N) {
  int gw = (blockIdx.x * blockDim.x + threadIdx.x) >> 6;
  int lane = threadIdx.x & 63;
  int nw = (gridDim.x * blockDim.x) >> 6;
  for (int n = gw; n < N; n += nw) {
    int s0 = off[n], s1 = off[n + 1];
    float ax = 0.f, ay = 0.f;
    for (int idx = s0; idx < s1; ++idx) {
      int src = csr_src[idx];
      float w = csr_w[idx];
      unsigned v = *(const unsigned*)&xbf[(size_t)src * H + lane * 2];
      ax += w * bf2f((unsigned short)(v & 0xffffu));
      ay += w * bf2f((unsigned short)(v >> 16));
    }
    unsigned o = (unsigned)f2bf(ax) | ((unsigned)f2bf(ay) << 16);
    *(unsigned*)&aggbf[(size_t)n * H + lane * 2] = o;
  }
}

// ---------------- LayerNorm+relu+residual: x = bf16(relu(LN(h)*g+b) + x) ----------------
__global__ __launch_bounds__(256) void ln_relu_res_bf_kernel(
    const float* __restrict__ h, unsigned short* __restrict__ xbf,
    const float* __restrict__ gamma, const float* __restrict__ beta, int N) {
  int gw = (blockIdx.x * blockDim.x + threadIdx.x) >> 6;
  int lane = threadIdx.x & 63;
  int nw = (gridDim.x * blockDim.x) >> 6;
  for (int n = gw; n < N; n += nw) {
    float2 v = *(const float2*)&h[(size_t)n * H + lane * 2];
    float tot = v.x + v.y;
#pragma unroll
    for (int o = 32; o > 0; o >>= 1) tot += __shfl_xor(tot, o, 64);
    float mu = tot * (1.0f / H);
    float d0 = v.x - mu, d1 = v.y - mu;
    float s2 = d0 * d0 + d1 * d1;
#pragma unroll
    for (int o = 32; o > 0; o >>= 1) s2 += __shfl_xor(s2, o, 64);
    float r = rsqrtf(s2 * (1.0f / H) + LN_EPS);
    float2 g = *(const float2*)&gamma[lane * 2];
    float2 b = *(const float2*)&beta[lane * 2];
    unsigned xo = *(const unsigned*)&xbf[(size_t)n * H + lane * 2];
    float o0 = fmaxf(d0 * r * g.x + b.x, 0.f) + bf2f((unsigned short)(xo & 0xffffu));
    float o1 = fmaxf(d1 * r * g.y + b.y, 0.f) + bf2f((unsigned short)(xo >> 16));
    unsigned res = (unsigned)f2bf(o0) | ((unsigned)f2bf(o1) << 16);
    *(unsigned*)&xbf[(size_t)n * H + lane * 2] = res;
  }
}

// ---------------- edge decoder: out[e] = relu(A[src]+B[dst]+af@Wd1c)·Wd2 + bd2 ----------------
__global__ __launch_bounds__(256) void edge_out_bf_kernel(
    const int* __restrict__ ei, const float* __restrict__ af,
    const unsigned short* __restrict__ A, const unsigned short* __restrict__ B,
    const float* __restrict__ Wd1c, const float* __restrict__ Wd2,
    const float* __restrict__ bd2, float* __restrict__ out, int E) {
  __shared__ float sWc[8][H];
  __shared__ float sW2[H];
  for (int i = threadIdx.x; i < 8 * H; i += blockDim.x) sWc[i >> 7][i & 127] = Wd1c[i];
  for (int i = threadIdx.x; i < H; i += blockDim.x) sW2[i] = Wd2[i];
  __syncthreads();
  int gw = (blockIdx.x * blockDim.x + threadIdx.x) >> 6;
  int lane = threadIdx.x & 63;
  int nw = (gridDim.x * blockDim.x) >> 6;
  float b2 = bd2[0];
  for (int e = gw; e < E; e += nw) {
    int s = ei[e], d = ei[E + e];
    unsigned va = *(const unsigned*)&A[(size_t)s * H + lane * 2];
    unsigned vb = *(const unsigned*)&B[(size_t)d * H + lane * 2];
    float t0 = bf2f((unsigned short)(va & 0xffffu)) + bf2f((unsigned short)(vb & 0xffffu));
    float t1 = bf2f((unsigned short)(va >> 16)) + bf2f((unsigned short)(vb >> 16));
#pragma unroll
    for (int i = 0; i < 8; ++i) {
      float a = af[(size_t)e * 8 + i];
      t0 += a * sWc[i][lane * 2];
      t1 += a * sWc[i][lane * 2 + 1];
    }
    t0 = fmaxf(t0, 0.f);
    t1 = fmaxf(t1, 0.f);
    float p = t0 * sW2[lane * 2] + t1 * sW2[lane * 2 + 1];
#pragma unroll
    for (int o = 32; o > 0; o >>= 1) p += __shfl_xor(p, o, 64);
    if (lane == 0) out[e] = p + b2;
  }
}

// ---------------- launch ----------------
extern "C" void kernel_launch(void* const* d_in, const int* in_sizes, int n_in, void* d_out,
                              int out_size, void* d_ws, size_t ws_size, hipStream_t stream) {
  const int* ei = (const int*)d_in[0];
  const float* af = (const float*)d_in[1];
  const float* h_old = (const float*)d_in[2];
  const float* Wf = (const float*)d_in[4];
  const float* bf = (const float*)d_in[5];
  const float* We1 = (const float*)d_in[6];
  const float* be1 = (const float*)d_in[7];
  const float* We2 = (const float*)d_in[8];
  const float* be2 = (const float*)d_in[9];
  const float* Wrel = (const float*)d_in[10];
  const float* brel = (const float*)d_in[11];
  const float* Wroot = (const float*)d_in[12];
  const float* gamma = (const float*)d_in[13];
  const float* beta = (const float*)d_in[14];
  const float* Wd1 = (const float*)d_in[15];
  const float* bd1 = (const float*)d_in[16];
  const float* Wd2 = (const float*)d_in[17];
  const float* bd2 = (const float*)d_in[18];
  const int N = in_sizes[2] / H;
  const int E = in_sizes[1] / 8;
  float* out = (float*)d_out;

  char* p = (char*)d_ws;
  auto alloc = [&](size_t b) { char* r = p; p += (b + 255) & ~(size_t)255; return r; };
  int* cnt = (int*)alloc((size_t)N * 4);
  int* pos = (int*)alloc((size_t)N * 4);
  int* off = (int*)alloc((size_t)(N + 1) * 4);
  int* csr_src = (int*)alloc((size_t)E * 4);
  float* csr_w = (float*)alloc((size_t)E * 4);
  float* ew = (float*)alloc((size_t)E * 4);
  float* cvec = (float*)alloc(H * 4);
  unsigned short* wpk = (unsigned short*)alloc((size_t)9 * 16384 * 2);
  unsigned short* xbf = (unsigned short*)alloc((size_t)N * H * 2);
  unsigned short* buf1 = (unsigned short*)alloc((size_t)N * H * 2);  // hbf / aggbf
  float* hbuf = (float*)alloc((size_t)N * H * 4);                    // h f32 / Abf+Bbf

  unsigned short* hbf = buf1;
  unsigned short* aggbf = buf1;
  unsigned short* Abf = (unsigned short*)hbuf;
  unsigned short* Bbf = (unsigned short*)hbuf + (size_t)N * H;

  hipLaunchKernelGGL(zero_int_kernel, dim3((N + 255) / 256), dim3(256), 0, stream, cnt, N);
  hipLaunchKernelGGL(prep_cvec_kernel, dim3(1), dim3(H), 0, stream, Wf, bf, cvec);
  hipLaunchKernelGGL(count_kernel, dim3((E + 255) / 256), dim3(256), 0, stream, ei, E, cnt);
  hipLaunchKernelGGL(scan_kernel, dim3(1), dim3(1024), 0, stream, cnt, off, pos, N);
  hipLaunchKernelGGL(edge_weight_kernel, dim3(2048), dim3(256), 0, stream, af, We1, be1, We2,
                     be2, ew, E);
  hipLaunchKernelGGL(fill_kernel, dim3((E + 255) / 256), dim3(256), 0, stream, ei, ew, E, pos,
                     csr_src, csr_w);
  hipLaunchKernelGGL(cvt_bf16_kernel, dim3(((long)N * H / 8 + 255) / 256), dim3(256), 0, stream,
                     h_old, hbf, (long)N * H);
  hipLaunchKernelGGL(pack_w_kernel, dim3(72), dim3(256), 0, stream, Wf, Wrel, Wroot, Wd1, wpk);

  int gblocks = (N + 255) / 256;
  // x = relu(h_old @ Wf2 + cvec) -> bf16
  hipLaunchKernelGGL((mfma_gemm_kernel<false, 1>), dim3(gblocks), dim3(256), 0, stream, hbf,
                     wpk, (const unsigned short*)nullptr, (const unsigned short*)nullptr, cvec,
                     xbf, N);

  for (int l = 0; l < 3; ++l) {
    hipLaunchKernelGGL(gather_agg_bf_kernel, dim3((N + 3) / 4), dim3(256), 0, stream, xbf, off,
                       csr_src, csr_w, aggbf, N);
    hipLaunchKernelGGL((mfma_gemm_kernel<true, 0>), dim3(gblocks), dim3(256), 0, stream, aggbf,
                       wpk + (size_t)(1 + l) * 16384, xbf, wpk + (size_t)(4 + l) * 16384,
                       brel + l * H, hbuf, N);
    hipLaunchKernelGGL(ln_relu_res_bf_kernel, dim3((N + 3) / 4), dim3(256), 0, stream, hbuf,
                       xbf, gamma + l * H, beta + l * H, N);
  }

  // decoder per-node projections: A = x@Wd1a + bd1 ; B = x@Wd1b  (bf16 outputs)
  hipLaunchKernelGGL((mfma_gemm_kernel<false, 2>), dim3(gblocks), dim3(256), 0, stream, xbf,
                     wpk + (size_t)7 * 16384, (const unsigned short*)nullptr,
                     (const unsigned short*)nullptr, bd1, Abf, N);
  hipLaunchKernelGGL((mfma_gemm_kernel<false, 2>), dim3(gblocks), dim3(256), 0, stream, xbf,
                     wpk + (size_t)8 * 16384, (const unsigned short*)nullptr,
                     (const unsigned short*)nullptr, (const float*)nullptr, Bbf, N);
  hipLaunchKernelGGL(edge_out_bf_kernel, dim3(4096), dim3(256), 0, stream, ei, af, Abf, Bbf,
                     Wd1 + 2 * H * H, Wd2, bd2, out, E);
}

// Round 3
// 512.893 us; speedup vs baseline: 1.7820x; 1.3422x over previous
//
#include <hip/hip_runtime.h>
#include <hip/hip_bf16.h>

#define H 128
#define LN_EPS 1e-5f

typedef __attribute__((ext_vector_type(8))) short bf16x8;
typedef __attribute__((ext_vector_type(4))) float f32x4;

static __device__ __forceinline__ unsigned short f2bf(float f) {
  unsigned u = __float_as_uint(f);
  unsigned r = (u + 0x7fff + ((u >> 16) & 1)) >> 16;
  return (unsigned short)r;
}
static __device__ __forceinline__ float bf2f(unsigned short s) {
  return __uint_as_float(((unsigned)s) << 16);
}

// ---------------- utility kernels ----------------

__global__ void zero_int_kernel(int* __restrict__ p, int n) {
  int i = blockIdx.x * blockDim.x + threadIdx.x;
  if (i < n) p[i] = 0;
}

// cvec[j] = bf[j] + sum_{r<128} Wf[r][j]   (the ones @ Wf[:128] term)
__global__ void prep_cvec_kernel(const float* __restrict__ Wf, const float* __restrict__ bf,
                                 float* __restrict__ cvec) {
  int j = threadIdx.x;
  float s = bf[j];
  for (int r = 0; r < H; ++r) s += Wf[r * H + j];
  cvec[j] = s;
}

__global__ void count_kernel(const int* __restrict__ ei, int E, int* __restrict__ cnt) {
  int e = blockIdx.x * blockDim.x + threadIdx.x;
  if (e < E) atomicAdd(&cnt[ei[E + e]], 1);  // dst = ei[1][e]
}

__global__ __launch_bounds__(1024) void scan_kernel(const int* __restrict__ cnt,
                                                    int* __restrict__ off,
                                                    int* __restrict__ pos, int N) {
  __shared__ int wtot[16];
  __shared__ int wbase[16];
  __shared__ int s_btot;
  __shared__ int s_carry;
  int tid = threadIdx.x, lane = tid & 63, wid = tid >> 6;
  if (tid == 0) s_carry = 0;
  __syncthreads();
  for (int base = 0; base < N; base += 4096) {
    int i0 = base + tid * 4;
    int v[4];
#pragma unroll
    for (int j = 0; j < 4; ++j) v[j] = (i0 + j < N) ? cnt[i0 + j] : 0;
    int s = v[0] + v[1] + v[2] + v[3];
    int incl = s;
#pragma unroll
    for (int o = 1; o < 64; o <<= 1) {
      int t = __shfl_up(incl, o, 64);
      if (lane >= o) incl += t;
    }
    if (lane == 63) wtot[wid] = incl;
    __syncthreads();
    if (tid == 0) {
      int run = 0;
      for (int w = 0; w < 16; ++w) { wbase[w] = run; run += wtot[w]; }
      s_btot = run;
    }
    __syncthreads();
    int e0 = s_carry + wbase[wid] + (incl - s);
#pragma unroll
    for (int j = 0; j < 4; ++j) {
      if (i0 + j < N) { off[i0 + j] = e0; pos[i0 + j] = e0; }
      e0 += v[j];
    }
    __syncthreads();
    if (tid == 0) s_carry += s_btot;
    __syncthreads();
  }
  if (tid == 0) off[N] = s_carry;
}

__global__ void fill_kernel(const int* __restrict__ ei, const float* __restrict__ ew, int E,
                            int* __restrict__ pos, int* __restrict__ csr_src,
                            float* __restrict__ csr_w) {
  int e = blockIdx.x * blockDim.x + threadIdx.x;
  if (e < E) {
    int d = ei[E + e];
    int p = atomicAdd(&pos[d], 1);
    csr_src[p] = ei[e];
    csr_w[p] = ew[e];
  }
}

// f32 -> bf16 bulk convert (n multiple of 8)
__global__ __launch_bounds__(256) void cvt_bf16_kernel(const float* __restrict__ in,
                                                       unsigned short* __restrict__ out,
                                                       long n) {
  long i = ((long)blockIdx.x * blockDim.x + threadIdx.x) * 8;
  if (i >= n) return;
  float4 v0 = *(const float4*)&in[i];
  float4 v1 = *(const float4*)&in[i + 4];
  unsigned short t[8];
  t[0] = f2bf(v0.x); t[1] = f2bf(v0.y); t[2] = f2bf(v0.z); t[3] = f2bf(v0.w);
  t[4] = f2bf(v1.x); t[5] = f2bf(v1.y); t[6] = f2bf(v1.z); t[7] = f2bf(v1.w);
  *(uint4*)&out[i] = *(uint4*)t;
}

// pack 9 [128x128] weight matrices into MFMA B-fragment layout:
// wpk[m*16384 + ((kk*8+nf)*64 + l)*8 + j] = bf16(W[kk*32 + (l>>4)*8 + j][nf*16 + (l&15)])
__global__ __launch_bounds__(256) void pack_w_kernel(const float* __restrict__ Wf,
                                                     const float* __restrict__ Wrel,
                                                     const float* __restrict__ Wroot,
                                                     const float* __restrict__ Wd1,
                                                     unsigned short* __restrict__ wpk) {
  int id = blockIdx.x * blockDim.x + threadIdx.x;  // 0 .. 9*2048-1
  if (id >= 9 * 2048) return;
  int l = id & 63, nf = (id >> 6) & 7, kk = (id >> 9) & 3, m = id >> 11;
  const float* src;
  if (m == 0) src = Wf + H * H;                       // Wf2 (h_old part)
  else if (m <= 3) src = Wrel + (size_t)(m - 1) * H * H;
  else if (m <= 6) src = Wroot + (size_t)(m - 4) * H * H;
  else src = Wd1 + (size_t)(m - 7) * H * H;           // Wd1a, Wd1b
  int col = nf * 16 + (l & 15);
  int kbase = kk * 32 + (l >> 4) * 8;
  unsigned short t[8];
#pragma unroll
  for (int j = 0; j < 8; ++j) t[j] = f2bf(src[(size_t)(kbase + j) * H + col]);
  *(uint4*)&wpk[(size_t)id * 8] = *(uint4*)t;
}

// ---------------- edge weight MLP v3: 16 lanes/edge, weights in registers ----------------
// ew[e] = sigmoid(relu(af@We1+be1)@We2+be2)
__global__ __launch_bounds__(256) void edge_weight_v3_kernel(
    const float* __restrict__ af, const float* __restrict__ We1, const float* __restrict__ be1,
    const float* __restrict__ We2, const float* __restrict__ be2, float* __restrict__ ew, int E) {
  int lane = threadIdx.x & 63;
  int sub = lane & 15;  // col group: cols sub*8 .. sub*8+7
  int grp = lane >> 4;  // which of 4 edges in this wave
  float w1[8][8], b1[8], w2[8];
#pragma unroll
  for (int i = 0; i < 8; ++i)
#pragma unroll
    for (int c = 0; c < 8; ++c) w1[i][c] = We1[i * H + sub * 8 + c];
#pragma unroll
  for (int c = 0; c < 8; ++c) { b1[c] = be1[sub * 8 + c]; w2[c] = We2[sub * 8 + c]; }
  float b2 = be2[0];
  int gw = (blockIdx.x * blockDim.x + threadIdx.x) >> 6;
  int nw = (gridDim.x * blockDim.x) >> 6;
  int n4 = (E + 3) >> 2;
  for (int e4 = gw; e4 < n4; e4 += nw) {
    int e = e4 * 4 + grp;
    bool valid = e < E;
    int ee = valid ? e : E - 1;
    float4 a0 = *(const float4*)&af[(size_t)ee * 8];
    float4 a1 = *(const float4*)&af[(size_t)ee * 8 + 4];
    float afv[8] = {a0.x, a0.y, a0.z, a0.w, a1.x, a1.y, a1.z, a1.w};
    float t[8];
#pragma unroll
    for (int c = 0; c < 8; ++c) t[c] = b1[c];
#pragma unroll
    for (int i = 0; i < 8; ++i)
#pragma unroll
      for (int c = 0; c < 8; ++c) t[c] += afv[i] * w1[i][c];
    float p = 0.f;
#pragma unroll
    for (int c = 0; c < 8; ++c) p += fmaxf(t[c], 0.f) * w2[c];
    p += __shfl_xor(p, 1, 64);
    p += __shfl_xor(p, 2, 64);
    p += __shfl_xor(p, 4, 64);
    p += __shfl_xor(p, 8, 64);
    if (valid && sub == 0) {
      float s = p + b2;
      ew[e] = 1.f / (1.f + expf(-s));
    }
  }
}

// ---------------- MFMA GEMM: Y = act(X1@W1 [+ X2@W2] + bias) ----------------
// X row-major bf16 [M,128]; W pre-packed fragment layout; OUT_MODE 0: f32, 1: bf16+relu, 2: bf16
template <bool DUAL, int OUT_MODE>
__global__ __launch_bounds__(256) void mfma_gemm_kernel(
    const unsigned short* __restrict__ X1, const unsigned short* __restrict__ Wp1,
    const unsigned short* __restrict__ X2, const unsigned short* __restrict__ Wp2,
    const float* __restrict__ bias, void* __restrict__ Yv, int M) {
  int l = threadIdx.x & 63, w = threadIdx.x >> 6;
  int lr = l & 15, lg = l >> 4;
  int m0 = blockIdx.x * 256 + w * 64;
  f32x4 acc[4][8] = {};
  const int nkk = DUAL ? 8 : 4;
  for (int kk = 0; kk < nkk; ++kk) {
    const unsigned short* X = (DUAL && kk >= 4) ? X2 : X1;
    const unsigned short* Wp = (DUAL && kk >= 4) ? Wp2 : Wp1;
    int k4 = kk & 3;
    bf16x8 a[4];
#pragma unroll
    for (int mi = 0; mi < 4; ++mi) {
      int row = m0 + mi * 16 + lr;
      if (row >= M) row = M - 1;
      a[mi] = *(const bf16x8*)&X[(size_t)row * H + k4 * 32 + lg * 8];
    }
#pragma unroll
    for (int nf = 0; nf < 8; ++nf) {
      bf16x8 b = *(const bf16x8*)&Wp[(size_t)(k4 * 8 + nf) * 512 + l * 8];
#pragma unroll
      for (int mi = 0; mi < 4; ++mi)
        acc[mi][nf] = __builtin_amdgcn_mfma_f32_16x16x32_bf16(a[mi], b, acc[mi][nf], 0, 0, 0);
    }
  }
  float bv[8];
#pragma unroll
  for (int nf = 0; nf < 8; ++nf) bv[nf] = bias ? bias[nf * 16 + lr] : 0.f;
#pragma unroll
  for (int mi = 0; mi < 4; ++mi) {
#pragma unroll
    for (int r = 0; r < 4; ++r) {
      int row = m0 + mi * 16 + lg * 4 + r;
      if (row < M) {
#pragma unroll
        for (int nf = 0; nf < 8; ++nf) {
          float v = acc[mi][nf][r] + bv[nf];
          if (OUT_MODE == 1) v = fmaxf(v, 0.f);
          int col = nf * 16 + lr;
          if (OUT_MODE == 0) ((float*)Yv)[(size_t)row * H + col] = v;
          else ((unsigned short*)Yv)[(size_t)row * H + col] = f2bf(v);
        }
      }
    }
  }
}

// ---------------- gather: agg[n] = sum_in-edges w * x[src]  (wave/node, 4-deep unroll) ----------------
__global__ __launch_bounds__(256) void gather_agg_bf_kernel(
    const unsigned short* __restrict__ xbf, const int* __restrict__ off,
    const int* __restrict__ csr_src, const float* __restrict__ csr_w,
    unsigned short* __restrict__ aggbf, int N) {
  int gw = (blockIdx.x * blockDim.x + threadIdx.x) >> 6;
  int lane = threadIdx.x & 63;
  int nw = (gridDim.x * blockDim.x) >> 6;
  for (int n = gw; n < N; n += nw) {
    int s0 = off[n], s1 = off[n + 1];
    float ax = 0.f, ay = 0.f;
    int idx = s0;
    for (; idx + 4 <= s1; idx += 4) {
      int src0 = csr_src[idx + 0], src1 = csr_src[idx + 1];
      int src2 = csr_src[idx + 2], src3 = csr_src[idx + 3];
      float w0 = csr_w[idx + 0], w1 = csr_w[idx + 1];
      float w2 = csr_w[idx + 2], w3 = csr_w[idx + 3];
      unsigned v0 = *(const unsigned*)&xbf[(size_t)src0 * H + lane * 2];
      unsigned v1 = *(const unsigned*)&xbf[(size_t)src1 * H + lane * 2];
      unsigned v2 = *(const unsigned*)&xbf[(size_t)src2 * H + lane * 2];
      unsigned v3 = *(const unsigned*)&xbf[(size_t)src3 * H + lane * 2];
      ax += w0 * bf2f((unsigned short)(v0 & 0xffffu));
      ay += w0 * bf2f((unsigned short)(v0 >> 16));
      ax += w1 * bf2f((unsigned short)(v1 & 0xffffu));
      ay += w1 * bf2f((unsigned short)(v1 >> 16));
      ax += w2 * bf2f((unsigned short)(v2 & 0xffffu));
      ay += w2 * bf2f((unsigned short)(v2 >> 16));
      ax += w3 * bf2f((unsigned short)(v3 & 0xffffu));
      ay += w3 * bf2f((unsigned short)(v3 >> 16));
    }
    for (; idx < s1; ++idx) {
      int src = csr_src[idx];
      float w = csr_w[idx];
      unsigned v = *(const unsigned*)&xbf[(size_t)src * H + lane * 2];
      ax += w * bf2f((unsigned short)(v & 0xffffu));
      ay += w * bf2f((unsigned short)(v >> 16));
    }
    unsigned o = (unsigned)f2bf(ax) | ((unsigned)f2bf(ay) << 16);
    *(unsigned*)&aggbf[(size_t)n * H + lane * 2] = o;
  }
}

// ---------------- LayerNorm+relu+residual: x = bf16(relu(LN(h)*g+b) + x) ----------------
__global__ __launch_bounds__(256) void ln_relu_res_bf_kernel(
    const float* __restrict__ h, unsigned short* __restrict__ xbf,
    const float* __restrict__ gamma, const float* __restrict__ beta, int N) {
  int gw = (blockIdx.x * blockDim.x + threadIdx.x) >> 6;
  int lane = threadIdx.x & 63;
  int nw = (gridDim.x * blockDim.x) >> 6;
  for (int n = gw; n < N; n += nw) {
    float2 v = *(const float2*)&h[(size_t)n * H + lane * 2];
    float tot = v.x + v.y;
#pragma unroll
    for (int o = 32; o > 0; o >>= 1) tot += __shfl_xor(tot, o, 64);
    float mu = tot * (1.0f / H);
    float d0 = v.x - mu, d1 = v.y - mu;
    float s2 = d0 * d0 + d1 * d1;
#pragma unroll
    for (int o = 32; o > 0; o >>= 1) s2 += __shfl_xor(s2, o, 64);
    float r = rsqrtf(s2 * (1.0f / H) + LN_EPS);
    float2 g = *(const float2*)&gamma[lane * 2];
    float2 b = *(const float2*)&beta[lane * 2];
    unsigned xo = *(const unsigned*)&xbf[(size_t)n * H + lane * 2];
    float o0 = fmaxf(d0 * r * g.x + b.x, 0.f) + bf2f((unsigned short)(xo & 0xffffu));
    float o1 = fmaxf(d1 * r * g.y + b.y, 0.f) + bf2f((unsigned short)(xo >> 16));
    unsigned res = (unsigned)f2bf(o0) | ((unsigned)f2bf(o1) << 16);
    *(unsigned*)&xbf[(size_t)n * H + lane * 2] = res;
  }
}

// ---------------- edge decoder v3: 16 lanes/edge, weights in registers ----------------
// out[e] = relu(A[src]+B[dst]+af@Wd1c)·Wd2 + bd2
__global__ __launch_bounds__(256) void edge_out_v3_kernel(
    const int* __restrict__ ei, const float* __restrict__ af,
    const unsigned short* __restrict__ A, const unsigned short* __restrict__ B,
    const float* __restrict__ Wd1c, const float* __restrict__ Wd2,
    const float* __restrict__ bd2, float* __restrict__ out, int E) {
  int lane = threadIdx.x & 63;
  int sub = lane & 15;
  int grp = lane >> 4;
  float wc[8][8], w2[8];
#pragma unroll
  for (int i = 0; i < 8; ++i)
#pragma unroll
    for (int c = 0; c < 8; ++c) wc[i][c] = Wd1c[i * H + sub * 8 + c];
#pragma unroll
  for (int c = 0; c < 8; ++c) w2[c] = Wd2[sub * 8 + c];
  float b2 = bd2[0];
  int gw = (blockIdx.x * blockDim.x + threadIdx.x) >> 6;
  int nw = (gridDim.x * blockDim.x) >> 6;
  int n4 = (E + 3) >> 2;
  for (int e4 = gw; e4 < n4; e4 += nw) {
    int e = e4 * 4 + grp;
    bool valid = e < E;
    int ee = valid ? e : E - 1;
    int s = ei[ee], d = ei[E + ee];
    uint4 va = *(const uint4*)&A[(size_t)s * H + sub * 8];
    uint4 vb = *(const uint4*)&B[(size_t)d * H + sub * 8];
    float4 a0 = *(const float4*)&af[(size_t)ee * 8];
    float4 a1 = *(const float4*)&af[(size_t)ee * 8 + 4];
    float afv[8] = {a0.x, a0.y, a0.z, a0.w, a1.x, a1.y, a1.z, a1.w};
    const unsigned* pa = (const unsigned*)&va;
    const unsigned* pb = (const unsigned*)&vb;
    float t[8];
#pragma unroll
    for (int q = 0; q < 4; ++q) {
      unsigned av = pa[q], bv = pb[q];
      t[q * 2 + 0] = bf2f((unsigned short)(av & 0xffffu)) + bf2f((unsigned short)(bv & 0xffffu));
      t[q * 2 + 1] = bf2f((unsigned short)(av >> 16)) + bf2f((unsigned short)(bv >> 16));
    }
#pragma unroll
    for (int i = 0; i < 8; ++i)
#pragma unroll
      for (int c = 0; c < 8; ++c) t[c] += afv[i] * wc[i][c];
    float p = 0.f;
#pragma unroll
    for (int c = 0; c < 8; ++c) p += fmaxf(t[c], 0.f) * w2[c];
    p += __shfl_xor(p, 1, 64);
    p += __shfl_xor(p, 2, 64);
    p += __shfl_xor(p, 4, 64);
    p += __shfl_xor(p, 8, 64);
    if (valid && sub == 0) out[e] = p + b2;
  }
}

// ---------------- launch ----------------
extern "C" void kernel_launch(void* const* d_in, const int* in_sizes, int n_in, void* d_out,
                              int out_size, void* d_ws, size_t ws_size, hipStream_t stream) {
  const int* ei = (const int*)d_in[0];
  const float* af = (const float*)d_in[1];
  const float* h_old = (const float*)d_in[2];
  const float* Wf = (const float*)d_in[4];
  const float* bf = (const float*)d_in[5];
  const float* We1 = (const float*)d_in[6];
  const float* be1 = (const float*)d_in[7];
  const float* We2 = (const float*)d_in[8];
  const float* be2 = (const float*)d_in[9];
  const float* Wrel = (const float*)d_in[10];
  const float* brel = (const float*)d_in[11];
  const float* Wroot = (const float*)d_in[12];
  const float* gamma = (const float*)d_in[13];
  const float* beta = (const float*)d_in[14];
  const float* Wd1 = (const float*)d_in[15];
  const float* bd1 = (const float*)d_in[16];
  const float* Wd2 = (const float*)d_in[17];
  const float* bd2 = (const float*)d_in[18];
  const int N = in_sizes[2] / H;
  const int E = in_sizes[1] / 8;
  float* out = (float*)d_out;

  char* p = (char*)d_ws;
  auto alloc = [&](size_t b) { char* r = p; p += (b + 255) & ~(size_t)255; return r; };
  int* cnt = (int*)alloc((size_t)N * 4);
  int* pos = (int*)alloc((size_t)N * 4);
  int* off = (int*)alloc((size_t)(N + 1) * 4);
  int* csr_src = (int*)alloc((size_t)E * 4);
  float* csr_w = (float*)alloc((size_t)E * 4);
  float* ew = (float*)alloc((size_t)E * 4);
  float* cvec = (float*)alloc(H * 4);
  unsigned short* wpk = (unsigned short*)alloc((size_t)9 * 16384 * 2);
  unsigned short* xbf = (unsigned short*)alloc((size_t)N * H * 2);
  unsigned short* buf1 = (unsigned short*)alloc((size_t)N * H * 2);  // hbf / aggbf
  float* hbuf = (float*)alloc((size_t)N * H * 4);                    // h f32 / Abf+Bbf

  unsigned short* hbf = buf1;
  unsigned short* aggbf = buf1;
  unsigned short* Abf = (unsigned short*)hbuf;
  unsigned short* Bbf = (unsigned short*)hbuf + (size_t)N * H;

  hipLaunchKernelGGL(zero_int_kernel, dim3((N + 255) / 256), dim3(256), 0, stream, cnt, N);
  hipLaunchKernelGGL(prep_cvec_kernel, dim3(1), dim3(H), 0, stream, Wf, bf, cvec);
  hipLaunchKernelGGL(count_kernel, dim3((E + 255) / 256), dim3(256), 0, stream, ei, E, cnt);
  hipLaunchKernelGGL(scan_kernel, dim3(1), dim3(1024), 0, stream, cnt, off, pos, N);
  hipLaunchKernelGGL(edge_weight_v3_kernel, dim3(4096), dim3(256), 0, stream, af, We1, be1,
                     We2, be2, ew, E);
  hipLaunchKernelGGL(fill_kernel, dim3((E + 255) / 256), dim3(256), 0, stream, ei, ew, E, pos,
                     csr_src, csr_w);
  hipLaunchKernelGGL(cvt_bf16_kernel, dim3(((long)N * H / 8 + 255) / 256), dim3(256), 0, stream,
                     h_old, hbf, (long)N * H);
  hipLaunchKernelGGL(pack_w_kernel, dim3(72), dim3(256), 0, stream, Wf, Wrel, Wroot, Wd1, wpk);

  int gblocks = (N + 255) / 256;
  // x = relu(h_old @ Wf2 + cvec) -> bf16
  hipLaunchKernelGGL((mfma_gemm_kernel<false, 1>), dim3(gblocks), dim3(256), 0, stream, hbf,
                     wpk, (const unsigned short*)nullptr, (const unsigned short*)nullptr, cvec,
                     xbf, N);

  for (int l = 0; l < 3; ++l) {
    hipLaunchKernelGGL(gather_agg_bf_kernel, dim3((N + 3) / 4), dim3(256), 0, stream, xbf, off,
                       csr_src, csr_w, aggbf, N);
    hipLaunchKernelGGL((mfma_gemm_kernel<true, 0>), dim3(gblocks), dim3(256), 0, stream, aggbf,
                       wpk + (size_t)(1 + l) * 16384, xbf, wpk + (size_t)(4 + l) * 16384,
                       brel + l * H, hbuf, N);
    hipLaunchKernelGGL(ln_relu_res_bf_kernel, dim3((N + 3) / 4), dim3(256), 0, stream, hbuf,
                       xbf, gamma + l * H, beta + l * H, N);
  }

  // decoder per-node projections: A = x@Wd1a + bd1 ; B = x@Wd1b  (bf16 outputs)
  hipLaunchKernelGGL((mfma_gemm_kernel<false, 2>), dim3(gblocks), dim3(256), 0, stream, xbf,
                     wpk + (size_t)7 * 16384, (const unsigned short*)nullptr,
                     (const unsigned short*)nullptr, bd1, Abf, N);
  hipLaunchKernelGGL((mfma_gemm_kernel<false, 2>), dim3(gblocks), dim3(256), 0, stream, xbf,
                     wpk + (size_t)8 * 16384, (const unsigned short*)nullptr,
                     (const unsigned short*)nullptr, (const float*)nullptr, Bbf, N);
  hipLaunchKernelGGL(edge_out_v3_kernel, dim3(4096), dim3(256), 0, stream, ei, af, Abf, Bbf,
                     Wd1 + 2 * H * H, Wd2, bd2, out, E);
}

// Round 4
// 511.228 us; speedup vs baseline: 1.7878x; 1.0033x over previous
//
#include <hip/hip_runtime.h>
#include <hip/hip_bf16.h>

#define H 128
#define LN_EPS 1e-5f

typedef __attribute__((ext_vector_type(8))) short bf16x8;
typedef __attribute__((ext_vector_type(4))) float f32x4;

static __device__ __forceinline__ unsigned short f2bf(float f) {
  unsigned u = __float_as_uint(f);
  unsigned r = (u + 0x7fff + ((u >> 16) & 1)) >> 16;
  return (unsigned short)r;
}
static __device__ __forceinline__ float bf2f(unsigned short s) {
  return __uint_as_float(((unsigned)s) << 16);
}

// ---------------- utility kernels ----------------

__global__ void zero_int_kernel(int* __restrict__ p, int n) {
  int i = blockIdx.x * blockDim.x + threadIdx.x;
  if (i < n) p[i] = 0;
}

// cvec[j] = bf[j] + sum_{r<128} Wf[r][j]   (the ones @ Wf[:128] term)
__global__ void prep_cvec_kernel(const float* __restrict__ Wf, const float* __restrict__ bf,
                                 float* __restrict__ cvec) {
  int j = threadIdx.x;
  float s = bf[j];
  for (int r = 0; r < H; ++r) s += Wf[r * H + j];
  cvec[j] = s;
}

__global__ void count_kernel(const int* __restrict__ ei, int E, int* __restrict__ cnt) {
  int e = blockIdx.x * blockDim.x + threadIdx.x;
  if (e < E) atomicAdd(&cnt[ei[E + e]], 1);  // dst = ei[1][e]
}

__global__ __launch_bounds__(1024) void scan_kernel(const int* __restrict__ cnt,
                                                    int* __restrict__ off,
                                                    int* __restrict__ pos, int N) {
  __shared__ int wtot[16];
  __shared__ int wbase[16];
  __shared__ int s_btot;
  __shared__ int s_carry;
  int tid = threadIdx.x, lane = tid & 63, wid = tid >> 6;
  if (tid == 0) s_carry = 0;
  __syncthreads();
  for (int base = 0; base < N; base += 4096) {
    int i0 = base + tid * 4;
    int v[4];
#pragma unroll
    for (int j = 0; j < 4; ++j) v[j] = (i0 + j < N) ? cnt[i0 + j] : 0;
    int s = v[0] + v[1] + v[2] + v[3];
    int incl = s;
#pragma unroll
    for (int o = 1; o < 64; o <<= 1) {
      int t = __shfl_up(incl, o, 64);
      if (lane >= o) incl += t;
    }
    if (lane == 63) wtot[wid] = incl;
    __syncthreads();
    if (tid == 0) {
      int run = 0;
      for (int w = 0; w < 16; ++w) { wbase[w] = run; run += wtot[w]; }
      s_btot = run;
    }
    __syncthreads();
    int e0 = s_carry + wbase[wid] + (incl - s);
#pragma unroll
    for (int j = 0; j < 4; ++j) {
      if (i0 + j < N) { off[i0 + j] = e0; pos[i0 + j] = e0; }
      e0 += v[j];
    }
    __syncthreads();
    if (tid == 0) s_carry += s_btot;
    __syncthreads();
  }
  if (tid == 0) off[N] = s_carry;
}

__global__ void fill_kernel(const int* __restrict__ ei, const float* __restrict__ ew, int E,
                            int* __restrict__ pos, int* __restrict__ csr_src,
                            float* __restrict__ csr_w) {
  int e = blockIdx.x * blockDim.x + threadIdx.x;
  if (e < E) {
    int d = ei[E + e];
    int p = atomicAdd(&pos[d], 1);
    csr_src[p] = ei[e];
    csr_w[p] = ew[e];
  }
}

// f32 -> bf16 bulk convert (n multiple of 8)
__global__ __launch_bounds__(256) void cvt_bf16_kernel(const float* __restrict__ in,
                                                       unsigned short* __restrict__ out,
                                                       long n) {
  long i = ((long)blockIdx.x * blockDim.x + threadIdx.x) * 8;
  if (i >= n) return;
  float4 v0 = *(const float4*)&in[i];
  float4 v1 = *(const float4*)&in[i + 4];
  unsigned short t[8];
  t[0] = f2bf(v0.x); t[1] = f2bf(v0.y); t[2] = f2bf(v0.z); t[3] = f2bf(v0.w);
  t[4] = f2bf(v1.x); t[5] = f2bf(v1.y); t[6] = f2bf(v1.z); t[7] = f2bf(v1.w);
  *(uint4*)&out[i] = *(uint4*)t;
}

// pack 9 [128x128] weight matrices into MFMA B-fragment layout:
// wpk[m*16384 + ((kk*8+nf)*64 + l)*8 + j] = bf16(W[kk*32 + (l>>4)*8 + j][nf*16 + (l&15)])
__global__ __launch_bounds__(256) void pack_w_kernel(const float* __restrict__ Wf,
                                                     const float* __restrict__ Wrel,
                                                     const float* __restrict__ Wroot,
                                                     const float* __restrict__ Wd1,
                                                     unsigned short* __restrict__ wpk) {
  int id = blockIdx.x * blockDim.x + threadIdx.x;  // 0 .. 9*2048-1
  if (id >= 9 * 2048) return;
  int l = id & 63, nf = (id >> 6) & 7, kk = (id >> 9) & 3, m = id >> 11;
  const float* src;
  if (m == 0) src = Wf + H * H;                       // Wf2 (h_old part)
  else if (m <= 3) src = Wrel + (size_t)(m - 1) * H * H;
  else if (m <= 6) src = Wroot + (size_t)(m - 4) * H * H;
  else src = Wd1 + (size_t)(m - 7) * H * H;           // Wd1a, Wd1b
  int col = nf * 16 + (l & 15);
  int kbase = kk * 32 + (l >> 4) * 8;
  unsigned short t[8];
#pragma unroll
  for (int j = 0; j < 8; ++j) t[j] = f2bf(src[(size_t)(kbase + j) * H + col]);
  *(uint4*)&wpk[(size_t)id * 8] = *(uint4*)t;
}

// ---------------- edge weight MLP v3: 16 lanes/edge, weights in registers ----------------
// ew[e] = sigmoid(relu(af@We1+be1)@We2+be2)
__global__ __launch_bounds__(256) void edge_weight_v3_kernel(
    const float* __restrict__ af, const float* __restrict__ We1, const float* __restrict__ be1,
    const float* __restrict__ We2, const float* __restrict__ be2, float* __restrict__ ew, int E) {
  int lane = threadIdx.x & 63;
  int sub = lane & 15;  // col group: cols sub*8 .. sub*8+7
  int grp = lane >> 4;  // which of 4 edges in this wave
  float w1[8][8], b1[8], w2[8];
#pragma unroll
  for (int i = 0; i < 8; ++i)
#pragma unroll
    for (int c = 0; c < 8; ++c) w1[i][c] = We1[i * H + sub * 8 + c];
#pragma unroll
  for (int c = 0; c < 8; ++c) { b1[c] = be1[sub * 8 + c]; w2[c] = We2[sub * 8 + c]; }
  float b2 = be2[0];
  int gw = (blockIdx.x * blockDim.x + threadIdx.x) >> 6;
  int nw = (gridDim.x * blockDim.x) >> 6;
  int n4 = (E + 3) >> 2;
  for (int e4 = gw; e4 < n4; e4 += nw) {
    int e = e4 * 4 + grp;
    bool valid = e < E;
    int ee = valid ? e : E - 1;
    float4 a0 = *(const float4*)&af[(size_t)ee * 8];
    float4 a1 = *(const float4*)&af[(size_t)ee * 8 + 4];
    float afv[8] = {a0.x, a0.y, a0.z, a0.w, a1.x, a1.y, a1.z, a1.w};
    float t[8];
#pragma unroll
    for (int c = 0; c < 8; ++c) t[c] = b1[c];
#pragma unroll
    for (int i = 0; i < 8; ++i)
#pragma unroll
      for (int c = 0; c < 8; ++c) t[c] += afv[i] * w1[i][c];
    float p = 0.f;
#pragma unroll
    for (int c = 0; c < 8; ++c) p += fmaxf(t[c], 0.f) * w2[c];
    p += __shfl_xor(p, 1, 64);
    p += __shfl_xor(p, 2, 64);
    p += __shfl_xor(p, 4, 64);
    p += __shfl_xor(p, 8, 64);
    if (valid && sub == 0) {
      float s = p + b2;
      ew[e] = 1.f / (1.f + expf(-s));
    }
  }
}

// ---------------- MFMA GEMM: Y = act(X1@W1 [+ X2@W2] + bias) ----------------
// X row-major bf16 [M,128]; W pre-packed fragment layout; OUT_MODE 0: f32, 1: bf16+relu, 2: bf16
template <bool DUAL, int OUT_MODE>
__global__ __launch_bounds__(256) void mfma_gemm_kernel(
    const unsigned short* __restrict__ X1, const unsigned short* __restrict__ Wp1,
    const unsigned short* __restrict__ X2, const unsigned short* __restrict__ Wp2,
    const float* __restrict__ bias, void* __restrict__ Yv, int M) {
  int l = threadIdx.x & 63, w = threadIdx.x >> 6;
  int lr = l & 15, lg = l >> 4;
  int m0 = blockIdx.x * 256 + w * 64;
  f32x4 acc[4][8] = {};
  const int nkk = DUAL ? 8 : 4;
  for (int kk = 0; kk < nkk; ++kk) {
    const unsigned short* X = (DUAL && kk >= 4) ? X2 : X1;
    const unsigned short* Wp = (DUAL && kk >= 4) ? Wp2 : Wp1;
    int k4 = kk & 3;
    bf16x8 a[4];
#pragma unroll
    for (int mi = 0; mi < 4; ++mi) {
      int row = m0 + mi * 16 + lr;
      if (row >= M) row = M - 1;
      a[mi] = *(const bf16x8*)&X[(size_t)row * H + k4 * 32 + lg * 8];
    }
#pragma unroll
    for (int nf = 0; nf < 8; ++nf) {
      bf16x8 b = *(const bf16x8*)&Wp[(size_t)(k4 * 8 + nf) * 512 + l * 8];
#pragma unroll
      for (int mi = 0; mi < 4; ++mi)
        acc[mi][nf] = __builtin_amdgcn_mfma_f32_16x16x32_bf16(a[mi], b, acc[mi][nf], 0, 0, 0);
    }
  }
  float bv[8];
#pragma unroll
  for (int nf = 0; nf < 8; ++nf) bv[nf] = bias ? bias[nf * 16 + lr] : 0.f;
#pragma unroll
  for (int mi = 0; mi < 4; ++mi) {
#pragma unroll
    for (int r = 0; r < 4; ++r) {
      int row = m0 + mi * 16 + lg * 4 + r;
      if (row < M) {
#pragma unroll
        for (int nf = 0; nf < 8; ++nf) {
          float v = acc[mi][nf][r] + bv[nf];
          if (OUT_MODE == 1) v = fmaxf(v, 0.f);
          int col = nf * 16 + lr;
          if (OUT_MODE == 0) ((float*)Yv)[(size_t)row * H + col] = v;
          else ((unsigned short*)Yv)[(size_t)row * H + col] = f2bf(v);
        }
      }
    }
  }
}

// ---------------- gather: agg[n] = sum_in-edges w * x[src]  (wave/node, 4-deep unroll) ----------------
__global__ __launch_bounds__(256) void gather_agg_bf_kernel(
    const unsigned short* __restrict__ xbf, const int* __restrict__ off,
    const int* __restrict__ csr_src, const float* __restrict__ csr_w,
    unsigned short* __restrict__ aggbf, int N) {
  int gw = (blockIdx.x * blockDim.x + threadIdx.x) >> 6;
  int lane = threadIdx.x & 63;
  int nw = (gridDim.x * blockDim.x) >> 6;
  for (int n = gw; n < N; n += nw) {
    int s0 = off[n], s1 = off[n + 1];
    float ax = 0.f, ay = 0.f;
    int idx = s0;
    for (; idx + 4 <= s1; idx += 4) {
      int src0 = csr_src[idx + 0], src1 = csr_src[idx + 1];
      int src2 = csr_src[idx + 2], src3 = csr_src[idx + 3];
      float w0 = csr_w[idx + 0], w1 = csr_w[idx + 1];
      float w2 = csr_w[idx + 2], w3 = csr_w[idx + 3];
      unsigned v0 = *(const unsigned*)&xbf[(size_t)src0 * H + lane * 2];
      unsigned v1 = *(const unsigned*)&xbf[(size_t)src1 * H + lane * 2];
      unsigned v2 = *(const unsigned*)&xbf[(size_t)src2 * H + lane * 2];
      unsigned v3 = *(const unsigned*)&xbf[(size_t)src3 * H + lane * 2];
      ax += w0 * bf2f((unsigned short)(v0 & 0xffffu));
      ay += w0 * bf2f((unsigned short)(v0 >> 16));
      ax += w1 * bf2f((unsigned short)(v1 & 0xffffu));
      ay += w1 * bf2f((unsigned short)(v1 >> 16));
      ax += w2 * bf2f((unsigned short)(v2 & 0xffffu));
      ay += w2 * bf2f((unsigned short)(v2 >> 16));
      ax += w3 * bf2f((unsigned short)(v3 & 0xffffu));
      ay += w3 * bf2f((unsigned short)(v3 >> 16));
    }
    for (; idx < s1; ++idx) {
      int src = csr_src[idx];
      float w = csr_w[idx];
      unsigned v = *(const unsigned*)&xbf[(size_t)src * H + lane * 2];
      ax += w * bf2f((unsigned short)(v & 0xffffu));
      ay += w * bf2f((unsigned short)(v >> 16));
    }
    unsigned o = (unsigned)f2bf(ax) | ((unsigned)f2bf(ay) << 16);
    *(unsigned*)&aggbf[(size_t)n * H + lane * 2] = o;
  }
}

// ---------------- LayerNorm+relu+residual: x = bf16(relu(LN(h)*g+b) + x) ----------------
__global__ __launch_bounds__(256) void ln_relu_res_bf_kernel(
    const float* __restrict__ h, unsigned short* __restrict__ xbf,
    const float* __restrict__ gamma, const float* __restrict__ beta, int N) {
  int gw = (blockIdx.x * blockDim.x + threadIdx.x) >> 6;
  int lane = threadIdx.x & 63;
  int nw = (gridDim.x * blockDim.x) >> 6;
  for (int n = gw; n < N; n += nw) {
    float2 v = *(const float2*)&h[(size_t)n * H + lane * 2];
    float tot = v.x + v.y;
#pragma unroll
    for (int o = 32; o > 0; o >>= 1) tot += __shfl_xor(tot, o, 64);
    float mu = tot * (1.0f / H);
    float d0 = v.x - mu, d1 = v.y - mu;
    float s2 = d0 * d0 + d1 * d1;
#pragma unroll
    for (int o = 32; o > 0; o >>= 1) s2 += __shfl_xor(s2, o, 64);
    float r = rsqrtf(s2 * (1.0f / H) + LN_EPS);
    float2 g = *(const float2*)&gamma[lane * 2];
    float2 b = *(const float2*)&beta[lane * 2];
    unsigned xo = *(const unsigned*)&xbf[(size_t)n * H + lane * 2];
    float o0 = fmaxf(d0 * r * g.x + b.x, 0.f) + bf2f((unsigned short)(xo & 0xffffu));
    float o1 = fmaxf(d1 * r * g.y + b.y, 0.f) + bf2f((unsigned short)(xo >> 16));
    unsigned res = (unsigned)f2bf(o0) | ((unsigned)f2bf(o1) << 16);
    *(unsigned*)&xbf[(size_t)n * H + lane * 2] = res;
  }
}

// ---------------- edge decoder v3: 16 lanes/edge, weights in registers ----------------
// out[e] = relu(A[src]+B[dst]+af@Wd1c)·Wd2 + bd2
__global__ __launch_bounds__(256) void edge_out_v3_kernel(
    const int* __restrict__ ei, const float* __restrict__ af,
    const unsigned short* __restrict__ A, const unsigned short* __restrict__ B,
    const float* __restrict__ Wd1c, const float* __restrict__ Wd2,
    const float* __restrict__ bd2, float* __restrict__ out, int E) {
  int lane = threadIdx.x & 63;
  int sub = lane & 15;
  int grp = lane >> 4;
  float wc[8][8], w2[8];
#pragma unroll
  for (int i = 0; i < 8; ++i)
#pragma unroll
    for (int c = 0; c < 8; ++c) wc[i][c] = Wd1c[i * H + sub * 8 + c];
#pragma unroll
  for (int c = 0; c < 8; ++c) w2[c] = Wd2[sub * 8 + c];
  float b2 = bd2[0];
  int gw = (blockIdx.x * blockDim.x + threadIdx.x) >> 6;
  int nw = (gridDim.x * blockDim.x) >> 6;
  int n4 = (E + 3) >> 2;
  for (int e4 = gw; e4 < n4; e4 += nw) {
    int e = e4 * 4 + grp;
    bool valid = e < E;
    int ee = valid ? e : E - 1;
    int s = ei[ee], d = ei[E + ee];
    uint4 va = *(const uint4*)&A[(size_t)s * H + sub * 8];
    uint4 vb = *(const uint4*)&B[(size_t)d * H + sub * 8];
    float4 a0 = *(const float4*)&af[(size_t)ee * 8];
    float4 a1 = *(const float4*)&af[(size_t)ee * 8 + 4];
    float afv[8] = {a0.x, a0.y, a0.z, a0.w, a1.x, a1.y, a1.z, a1.w};
    const unsigned* pa = (const unsigned*)&va;
    const unsigned* pb = (const unsigned*)&vb;
    float t[8];
#pragma unroll
    for (int q = 0; q < 4; ++q) {
      unsigned av = pa[q], bv = pb[q];
      t[q * 2 + 0] = bf2f((unsigned short)(av & 0xffffu)) + bf2f((unsigned short)(bv & 0xffffu));
      t[q * 2 + 1] = bf2f((unsigned short)(av >> 16)) + bf2f((unsigned short)(bv >> 16));
    }
#pragma unroll
    for (int i = 0; i < 8; ++i)
#pragma unroll
      for (int c = 0; c < 8; ++c) t[c] += afv[i] * wc[i][c];
    float p = 0.f;
#pragma unroll
    for (int c = 0; c < 8; ++c) p += fmaxf(t[c], 0.f) * w2[c];
    p += __shfl_xor(p, 1, 64);
    p += __shfl_xor(p, 2, 64);
    p += __shfl_xor(p, 4, 64);
    p += __shfl_xor(p, 8, 64);
    if (valid && sub == 0) out[e] = p + b2;
  }
}

// ---------------- launch ----------------
extern "C" void kernel_launch(void* const* d_in, const int* in_sizes, int n_in, void* d_out,
                              int out_size, void* d_ws, size_t ws_size, hipStream_t stream) {
  const int* ei = (const int*)d_in[0];
  const float* af = (const float*)d_in[1];
  const float* h_old = (const float*)d_in[2];
  const float* Wf = (const float*)d_in[4];
  const float* bf = (const float*)d_in[5];
  const float* We1 = (const float*)d_in[6];
  const float* be1 = (const float*)d_in[7];
  const float* We2 = (const float*)d_in[8];
  const float* be2 = (const float*)d_in[9];
  const float* Wrel = (const float*)d_in[10];
  const float* brel = (const float*)d_in[11];
  const float* Wroot = (const float*)d_in[12];
  const float* gamma = (const float*)d_in[13];
  const float* beta = (const float*)d_in[14];
  const float* Wd1 = (const float*)d_in[15];
  const float* bd1 = (const float*)d_in[16];
  const float* Wd2 = (const float*)d_in[17];
  const float* bd2 = (const float*)d_in[18];
  const int N = in_sizes[2] / H;
  const int E = in_sizes[1] / 8;
  float* out = (float*)d_out;

  char* p = (char*)d_ws;
  auto alloc = [&](size_t b) { char* r = p; p += (b + 255) & ~(size_t)255; return r; };
  int* cnt = (int*)alloc((size_t)N * 4);
  int* pos = (int*)alloc((size_t)N * 4);
  int* off = (int*)alloc((size_t)(N + 1) * 4);
  int* csr_src = (int*)alloc((size_t)E * 4);
  float* csr_w = (float*)alloc((size_t)E * 4);
  float* ew = (float*)alloc((size_t)E * 4);
  float* cvec = (float*)alloc(H * 4);
  unsigned short* wpk = (unsigned short*)alloc((size_t)9 * 16384 * 2);
  unsigned short* xbf = (unsigned short*)alloc((size_t)N * H * 2);
  unsigned short* buf1 = (unsigned short*)alloc((size_t)N * H * 2);  // hbf / aggbf
  float* hbuf = (float*)alloc((size_t)N * H * 4);                    // h f32 / Abf+Bbf

  unsigned short* hbf = buf1;
  unsigned short* aggbf = buf1;
  unsigned short* Abf = (unsigned short*)hbuf;
  unsigned short* Bbf = (unsigned short*)hbuf + (size_t)N * H;

  hipLaunchKernelGGL(zero_int_kernel, dim3((N + 255) / 256), dim3(256), 0, stream, cnt, N);
  hipLaunchKernelGGL(prep_cvec_kernel, dim3(1), dim3(H), 0, stream, Wf, bf, cvec);
  hipLaunchKernelGGL(count_kernel, dim3((E + 255) / 256), dim3(256), 0, stream, ei, E, cnt);
  hipLaunchKernelGGL(scan_kernel, dim3(1), dim3(1024), 0, stream, cnt, off, pos, N);
  hipLaunchKernelGGL(edge_weight_v3_kernel, dim3(4096), dim3(256), 0, stream, af, We1, be1,
                     We2, be2, ew, E);
  hipLaunchKernelGGL(fill_kernel, dim3((E + 255) / 256), dim3(256), 0, stream, ei, ew, E, pos,
                     csr_src, csr_w);
  hipLaunchKernelGGL(cvt_bf16_kernel, dim3(((long)N * H / 8 + 255) / 256), dim3(256), 0, stream,
                     h_old, hbf, (long)N * H);
  hipLaunchKernelGGL(pack_w_kernel, dim3(72), dim3(256), 0, stream, Wf, Wrel, Wroot, Wd1, wpk);

  int gblocks = (N + 255) / 256;
  // x = relu(h_old @ Wf2 + cvec) -> bf16
  hipLaunchKernelGGL((mfma_gemm_kernel<false, 1>), dim3(gblocks), dim3(256), 0, stream, hbf,
                     wpk, (const unsigned short*)nullptr, (const unsigned short*)nullptr, cvec,
                     xbf, N);

  for (int l = 0; l < 3; ++l) {
    hipLaunchKernelGGL(gather_agg_bf_kernel, dim3((N + 3) / 4), dim3(256), 0, stream, xbf, off,
                       csr_src, csr_w, aggbf, N);
    hipLaunchKernelGGL((mfma_gemm_kernel<true, 0>), dim3(gblocks), dim3(256), 0, stream, aggbf,
                       wpk + (size_t)(1 + l) * 16384, xbf, wpk + (size_t)(4 + l) * 16384,
                       brel + l * H, hbuf, N);
    hipLaunchKernelGGL(ln_relu_res_bf_kernel, dim3((N + 3) / 4), dim3(256), 0, stream, hbuf,
                       xbf, gamma + l * H, beta + l * H, N);
  }

  // decoder per-node projections: A = x@Wd1a + bd1 ; B = x@Wd1b  (bf16 outputs)
  hipLaunchKernelGGL((mfma_gemm_kernel<false, 2>), dim3(gblocks), dim3(256), 0, stream, xbf,
                     wpk + (size_t)7 * 16384, (const unsigned short*)nullptr,
                     (const unsigned short*)nullptr, bd1, Abf, N);
  hipLaunchKernelGGL((mfma_gemm_kernel<false, 2>), dim3(gblocks), dim3(256), 0, stream, xbf,
                     wpk + (size_t)8 * 16384, (const unsigned short*)nullptr,
                     (const unsigned short*)nullptr, (const float*)nullptr, Bbf, N);
  hipLaunchKernelGGL(edge_out_v3_kernel, dim3(4096), dim3(256), 0, stream, ei, af, Abf, Bbf,
                     Wd1 + 2 * H * H, Wd2, bd2, out, E);
}